// Round 3
// baseline (3945.895 us; speedup 1.0000x reference)
//
#include <hip/hip_runtime.h>

#define B_ 128
#define T_ 2048

typedef float vf32 __attribute__((ext_vector_type(32)));
typedef float vf16 __attribute__((ext_vector_type(16)));

__device__ __forceinline__ float fast_sigmoid(float x){
    return 1.0f / (1.0f + __expf(-x));
}
__device__ __forceinline__ float fast_tanh(float x){
    float a = fabsf(x);
    float e = __expf(2.0f*a);
    float r = 1.0f - 2.0f/(e + 1.0f);   // e=inf -> r=1, no NaN
    return (x < 0.0f) ? -r : r;
}

// ---------------------------------------------------------------------------
// Scan kernel: one workgroup per batch element b.
// threads   0..255 : LSTM  (thread g owns gate g; Wih row + Whh row in VGPRs)
// threads 256..511 : transition MLP, pipelined one step behind the LSTM
//
// Weights are held in clang ext_vector_type SSA values (wA0..wA2, wB, wC),
// constant subscripts only. 144 weight floats/lane + ~45 temps need ~190
// VGPRs. The hard cap for a 512-thread block is 256 (2 waves/SIMD), but the
// backend's occupancy heuristic was still targeting more waves and spilling
// (R1: VGPR=100, R2: VGPR=116 -- weight reloads every one of 2048 serial
// steps made the kernel L1-scratch-BW bound at ~3400 cy/step).
// amdgpu_waves_per_eu(2,2) pins the occupancy target to exactly what the
// 128-block grid delivers (1 block/CU), freeing regalloc to use 256 VGPRs.
// ---------------------------------------------------------------------------
__global__ __launch_bounds__(512)
__attribute__((amdgpu_waves_per_eu(2, 2)))
void scan_kernel(
    const float* __restrict__ obs,
    const float* __restrict__ Wih,
    const float* __restrict__ Whh,
    const float* __restrict__ bih,
    const float* __restrict__ bhh,
    const float* __restrict__ tw1,
    const float* __restrict__ tb1,
    const float* __restrict__ tg,
    const float* __restrict__ tbeta,
    const float* __restrict__ tw2,
    const float* __restrict__ tb2,
    const float* __restrict__ tw3,
    const float* __restrict__ tb3,
    const float* __restrict__ z0m,
    const float* __restrict__ z0lv,
    float* __restrict__ out_tm,
    float* __restrict__ out_tlv)
{
    __shared__ __align__(16) float comb_s[2][72];   // [0..63]=h, [64..68]=z, [69..71]=0 pad
    __shared__ __align__(16) float obs_s[2][32];
    __shared__ float gates_s[256];
    __shared__ __align__(16) float h1_s[128];
    __shared__ float part_s[256];
    __shared__ float lnp[4];

    const int tid = threadIdx.x;
    const int b   = blockIdx.x;

    // Register-resident weights (SSA vector values, constant-index only):
    // LSTM lane (tid<256):  wA0 = Wih row (32), wA1 = Whh[0..31], wA2 = Whh[32..63]
    // trans lane (q<128):   wA0 = t_w1[0..31], wA1 = t_w1[32..63], wA2[0..4] = t_w1[64..68], rest 0
    // wB = t_w2 quarter-row (all trans lanes);  wC = t_w3 sixteenth (q<40)
    vf32 wA0, wA1, wA2, wB;
    vf16 wC;
    #pragma unroll
    for (int k = 0; k < 32; k++) { wA0[k] = 0.f; wA1[k] = 0.f; wA2[k] = 0.f; wB[k] = 0.f; }
    #pragma unroll
    for (int k = 0; k < 16; k++) wC[k] = 0.f;

    float biasg = 0.f, b1r = 0.f, gr = 0.f, betar = 0.f, b2r = 0.f, b3r = 0.f;
    float c_st = 0.f;
    float a1v  = 0.f;
    float ld_carry = 0.f;

    if (tid < 256) {
        biasg = bih[tid] + bhh[tid];
        #pragma unroll
        for (int k = 0; k < 32; k++) wA0[k] = Wih[tid*32 + k];
        #pragma unroll
        for (int k = 0; k < 32; k++) wA1[k] = Whh[tid*64 + k];
        #pragma unroll
        for (int k = 0; k < 32; k++) wA2[k] = Whh[tid*64 + 32 + k];
    } else {
        const int q = tid - 256;
        if (q < 128) {
            #pragma unroll
            for (int k = 0; k < 32; k++) wA0[k] = tw1[q*69 + k];
            #pragma unroll
            for (int k = 0; k < 32; k++) wA1[k] = tw1[q*69 + 32 + k];
            #pragma unroll
            for (int k = 0; k < 5;  k++) wA2[k] = tw1[q*69 + 64 + k];
            b1r = tb1[q]; gr = tg[q]; betar = tbeta[q];
        }
        {
            const int j = q & 63, p = q >> 6;
            #pragma unroll
            for (int k = 0; k < 32; k++) wB[k] = tw2[j*128 + p*32 + k];
        }
        if (q < 64) b2r = tb2[q];
        if (q < 40) {
            const int j = q >> 2, pp = q & 3;
            #pragma unroll
            for (int k = 0; k < 16; k++) wC[k] = tw3[j*64 + pp*16 + k];
            b3r = tb3[j];
        }
    }

    // LDS / output init
    if (tid < 64) comb_s[1][tid] = 0.f;           // h_{-1} = 0 (read at i=0)
    if (tid < 5) {
        comb_s[1][64 + tid] = z0m[tid];           // z for first trans step (t=1)
        out_tm [(size_t)b*T_*5 + tid] = z0m[tid];   // trans_means[t=0]  = z0_mean
        out_tlv[(size_t)b*T_*5 + tid] = z0lv[tid];  // trans_logvars[0]  = z0_log_var
    }
    if (tid < 3) { comb_s[0][69 + tid] = 0.f; comb_s[1][69 + tid] = 0.f; }
    if (tid >= 64 && tid < 69) comb_s[0][tid] = 0.f;   // z slot of buf 0 (defensive init)
    if (tid < 32) {
        obs_s[0][tid] = obs[(size_t)b*T_*32 + tid];       // t=0
        ld_carry      = obs[((size_t)b*T_ + 1)*32 + tid]; // t=1 in flight
    }
    __syncthreads();

    for (int i = 0; i <= T_; ++i) {
        const int cur = i & 1, prev = cur ^ 1;
        const bool lstm_on  = (i < T_);
        const bool trans_on = (i >= 2);   // processes t_tr = i-1 in [1, T-1]

        // ---- seg1: LSTM gate matvec  ||  trans matvec1 + LN partial reduce ----
        if (tid < 256) {
            if (lstm_on) {
                float acc0 = biasg, acc1 = 0.f, acc2 = 0.f, acc3 = 0.f;
                const float4* ob4 = (const float4*)obs_s[cur];
                #pragma unroll
                for (int k4 = 0; k4 < 8; k4++) {
                    float4 o = ob4[k4];
                    acc0 += wA0[k4*4+0]*o.x;
                    acc1 += wA0[k4*4+1]*o.y;
                    acc2 += wA0[k4*4+2]*o.z;
                    acc3 += wA0[k4*4+3]*o.w;
                }
                const float4* hb4 = (const float4*)comb_s[prev];
                #pragma unroll
                for (int k4 = 0; k4 < 8; k4++) {
                    float4 h = hb4[k4];
                    acc0 += wA1[k4*4+0]*h.x;
                    acc1 += wA1[k4*4+1]*h.y;
                    acc2 += wA1[k4*4+2]*h.z;
                    acc3 += wA1[k4*4+3]*h.w;
                }
                #pragma unroll
                for (int k4 = 0; k4 < 8; k4++) {
                    float4 h = hb4[8 + k4];
                    acc0 += wA2[k4*4+0]*h.x;
                    acc1 += wA2[k4*4+1]*h.y;
                    acc2 += wA2[k4*4+2]*h.z;
                    acc3 += wA2[k4*4+3]*h.w;
                }
                gates_s[tid] = (acc0 + acc1) + (acc2 + acc3);
            }
        } else {
            const int q = tid - 256;
            if (trans_on && q < 128) {
                float acc0 = b1r, acc1 = 0.f, acc2 = 0.f, acc3 = 0.f;
                const float4* cb4 = (const float4*)comb_s[prev];
                #pragma unroll
                for (int k4 = 0; k4 < 8; k4++) {
                    float4 cv = cb4[k4];
                    acc0 += wA0[k4*4+0]*cv.x;
                    acc1 += wA0[k4*4+1]*cv.y;
                    acc2 += wA0[k4*4+2]*cv.z;
                    acc3 += wA0[k4*4+3]*cv.w;
                }
                #pragma unroll
                for (int k4 = 0; k4 < 8; k4++) {
                    float4 cv = cb4[8 + k4];
                    acc0 += wA1[k4*4+0]*cv.x;
                    acc1 += wA1[k4*4+1]*cv.y;
                    acc2 += wA1[k4*4+2]*cv.z;
                    acc3 += wA1[k4*4+3]*cv.w;
                }
                #pragma unroll
                for (int k4 = 0; k4 < 2; k4++) {
                    // elements 69..71 of comb_s are zero-padded; wA2[5..7] are zero
                    float4 cv = cb4[16 + k4];
                    acc0 += wA2[k4*4+0]*cv.x;
                    acc1 += wA2[k4*4+1]*cv.y;
                    acc2 += wA2[k4*4+2]*cv.z;
                    acc3 += wA2[k4*4+3]*cv.w;
                }
                a1v = (acc0 + acc1) + (acc2 + acc3);
                float s1 = a1v, s2 = a1v*a1v;
                #pragma unroll
                for (int m = 1; m < 64; m <<= 1) {
                    s1 += __shfl_xor(s1, m, 64);
                    s2 += __shfl_xor(s2, m, 64);
                }
                const int wv = (tid >> 6) - 4;   // 0 or 1
                if ((tid & 63) == 0) { lnp[wv*2] = s1; lnp[wv*2 + 1] = s2; }
            }
        }
        __syncthreads();

        // ---- seg2: LSTM activations/state  ||  trans layernorm + tanh ----
        if (tid < 64) {
            if (lstm_on) {
                float iv = fast_sigmoid(gates_s[tid]);
                float fv = fast_sigmoid(gates_s[64 + tid]);
                float gv = fast_tanh   (gates_s[128 + tid]);
                float ov = fast_sigmoid(gates_s[192 + tid]);
                c_st = fv*c_st + iv*gv;
                comb_s[cur][tid] = ov * fast_tanh(c_st);
            }
        } else if (tid >= 256 && tid < 384) {
            if (trans_on) {
                float mean = (lnp[0] + lnp[2]) * (1.0f/128.0f);
                float ms   = (lnp[1] + lnp[3]) * (1.0f/128.0f);
                float var  = fmaxf(ms - mean*mean, 0.0f);
                float rs   = rsqrtf(var + 1e-5f);
                h1_s[tid - 256] = fast_tanh((a1v - mean)*rs*gr + betar);
            }
        }
        __syncthreads();

        // ---- seg3: trans matvec2 partials  ||  LSTM waves prefetch obs ----
        if (tid >= 256) {
            if (trans_on) {
                const int q = tid - 256, p = q >> 6;
                float acc0 = 0.f, acc1 = 0.f, acc2 = 0.f, acc3 = 0.f;
                const float4* h14 = (const float4*)(h1_s + p*32);
                #pragma unroll
                for (int k4 = 0; k4 < 8; k4++) {
                    float4 hv = h14[k4];
                    acc0 += wB[k4*4+0]*hv.x;
                    acc1 += wB[k4*4+1]*hv.y;
                    acc2 += wB[k4*4+2]*hv.z;
                    acc3 += wB[k4*4+3]*hv.w;
                }
                part_s[q] = (acc0 + acc1) + (acc2 + acc3);
            }
        } else if (tid < 32) {
            const int t_w = i + 1, t_l = i + 2;
            if (t_w < T_) obs_s[t_w & 1][tid] = ld_carry;
            if (t_l < T_) ld_carry = obs[((size_t)b*T_ + t_l)*32 + tid];
        }
        __syncthreads();

        // ---- seg4 (wave 4 only, shuffle-based): h2, matvec3, outputs, z ----
        if (trans_on && tid >= 256 && tid < 320) {
            const int q = tid & 63;
            float h2v = fast_tanh(b2r + part_s[q] + part_s[64+q]
                                      + part_s[128+q] + part_s[192+q]);
            // lane q holds h2[q]; lane q computes partial dot of t_w3 row (q>>2)
            // over input chunk (q&3)*16 .. +15, gathered via shuffles.
            const int pp = q & 3;
            float acc = 0.f;
            #pragma unroll
            for (int k = 0; k < 16; k++)
                acc += wC[k] * __shfl(h2v, pp*16 + k, 64);
            acc += __shfl_xor(acc, 1, 64);
            acc += __shfl_xor(acc, 2, 64);   // lanes 4j..4j+3 now hold row-j total
            if (pp == 0 && q < 40) {
                const int j = q >> 2;        // 0..9
                float val = b3r + acc;
                const int t_tr = i - 1;
                const size_t row = (size_t)b*T_ + t_tr;
                if (j < 5) {
                    comb_s[cur][64 + j] = val;                      // z feedback
                    out_tm[row*5 + j] = val;
                } else {
                    out_tlv[row*5 + (j - 5)] = fminf(10.0f, fmaxf(-10.0f, val));
                }
            }
        }
        __syncthreads();
    }
}

// ---------------------------------------------------------------------------
// Observation decoder: one wave per row; weights in static LDS (~60 KB);
// h1/h2 are staged once per row into a per-wave LDS strip and re-read as
// BROADCAST float4 loads (same address across lanes = conflict-free, one DS
// op per 4 values). Accumulators split 4-way to break the serial FMA chain.
// ---------------------------------------------------------------------------
#define DEC_BLOCKS 512

__global__ __launch_bounds__(512) void dec_kernel(
    const float* __restrict__ ow1,
    const float* __restrict__ ob1,
    const float* __restrict__ og,
    const float* __restrict__ obeta,
    const float* __restrict__ ow2,
    const float* __restrict__ ob2,
    const float* __restrict__ ow3,
    const float* __restrict__ ob3,
    const float* __restrict__ tmeans,
    float* __restrict__ out_om,
    float* __restrict__ out_olv)
{
    __shared__ float w1s[640];    // [j*5+k]
    __shared__ float b1s[128], gs[128], bes[128];
    __shared__ float w2s[8192];   // [k*64+j] transposed
    __shared__ float b2s[64];
    __shared__ float w3s[4096];   // [k*64+j] transposed
    __shared__ float b3s[64];
    __shared__ __align__(16) float h1s[8][128];   // per-wave h1 strip
    __shared__ __align__(16) float h2s[8][64];    // per-wave h2 strip

    const int tid = threadIdx.x;
    for (int idx = tid; idx < 640; idx += 512) w1s[idx] = ow1[idx];
    for (int idx = tid; idx < 128; idx += 512) {
        b1s[idx] = ob1[idx]; gs[idx] = og[idx]; bes[idx] = obeta[idx];
    }
    for (int idx = tid; idx < 8192; idx += 512) {
        int k = idx >> 6, j = idx & 63;
        w2s[idx] = ow2[j*128 + k];
    }
    for (int idx = tid; idx < 4096; idx += 512) {
        int k = idx >> 6, j = idx & 63;
        w3s[idx] = ow3[j*64 + k];
    }
    for (int idx = tid; idx < 64; idx += 512) { b2s[idx] = ob2[idx]; b3s[idx] = ob3[idx]; }
    __syncthreads();

    const int lane   = tid & 63;
    const int wv     = tid >> 6;
    const int gwave  = (blockIdx.x * 512 + tid) >> 6;
    const int nwaves = DEC_BLOCKS * 8;
    const int j0 = lane, j1 = lane + 64;

    for (int row = gwave; row < B_*T_; row += nwaves) {
        const float z0v = tmeans[(size_t)row*5 + 0];
        const float z1v = tmeans[(size_t)row*5 + 1];
        const float z2v = tmeans[(size_t)row*5 + 2];
        const float z3v = tmeans[(size_t)row*5 + 3];
        const float z4v = tmeans[(size_t)row*5 + 4];

        // layer 1 (5 -> 128): lane holds outputs j0 and j1
        float a = b1s[j0] + w1s[j0*5+0]*z0v + w1s[j0*5+1]*z1v + w1s[j0*5+2]*z2v
                + w1s[j0*5+3]*z3v + w1s[j0*5+4]*z4v;
        float bb = b1s[j1] + w1s[j1*5+0]*z0v + w1s[j1*5+1]*z1v + w1s[j1*5+2]*z2v
                 + w1s[j1*5+3]*z3v + w1s[j1*5+4]*z4v;
        float s1 = a + bb, s2 = a*a + bb*bb;
        #pragma unroll
        for (int m = 1; m < 64; m <<= 1) {
            s1 += __shfl_xor(s1, m, 64);
            s2 += __shfl_xor(s2, m, 64);
        }
        const float mean = s1 * (1.0f/128.0f);
        const float var  = fmaxf(s2 * (1.0f/128.0f) - mean*mean, 0.0f);
        const float rs   = rsqrtf(var + 1e-5f);
        const float h1a  = fast_tanh((a  - mean)*rs*gs[j0] + bes[j0]);
        const float h1b  = fast_tanh((bb - mean)*rs*gs[j1] + bes[j1]);

        // stage h1 into the wave's private LDS strip (wave-synchronous)
        h1s[wv][lane]      = h1a;
        h1s[wv][64 + lane] = h1b;
        __builtin_amdgcn_wave_barrier();

        // layer 2 (128 -> 64): lane computes output j = lane.
        float acc2a = b2s[lane], acc2b = 0.f, acc2c = 0.f, acc2d = 0.f;
        const float4* h14 = (const float4*)(h1s[wv]);
        #pragma unroll
        for (int k4 = 0; k4 < 32; k4++) {
            float4 h = h14[k4];
            acc2a += h.x * w2s[(k4*4+0)*64 + lane];
            acc2b += h.y * w2s[(k4*4+1)*64 + lane];
            acc2c += h.z * w2s[(k4*4+2)*64 + lane];
            acc2d += h.w * w2s[(k4*4+3)*64 + lane];
        }
        const float h2v = fast_tanh(acc2a + acc2b + acc2c + acc2d);

        h2s[wv][lane] = h2v;
        __builtin_amdgcn_wave_barrier();

        // layer 3 (64 -> 64): lane computes output j = lane
        float acc3a = b3s[lane], acc3b = 0.f, acc3c = 0.f, acc3d = 0.f;
        const float4* h24 = (const float4*)(h2s[wv]);
        #pragma unroll
        for (int k4 = 0; k4 < 16; k4++) {
            float4 h = h24[k4];
            acc3a += h.x * w3s[(k4*4+0)*64 + lane];
            acc3b += h.y * w3s[(k4*4+1)*64 + lane];
            acc3c += h.z * w3s[(k4*4+2)*64 + lane];
            acc3d += h.w * w3s[(k4*4+3)*64 + lane];
        }
        const float acc3 = acc3a + acc3b + acc3c + acc3d;

        if (lane < 32) {
            out_om[(size_t)row*32 + lane] = acc3;
        } else {
            out_olv[(size_t)row*32 + (lane - 32)] = fminf(10.0f, fmaxf(-10.0f, acc3));
        }
    }
}

extern "C" void kernel_launch(void* const* d_in, const int* in_sizes, int n_in,
                              void* d_out, int out_size, void* d_ws, size_t ws_size,
                              hipStream_t stream) {
    const float* obs  = (const float*)d_in[0];
    const float* Wih  = (const float*)d_in[1];
    const float* Whh  = (const float*)d_in[2];
    const float* bih  = (const float*)d_in[3];
    const float* bhh  = (const float*)d_in[4];
    const float* tw1  = (const float*)d_in[5];
    const float* tb1  = (const float*)d_in[6];
    const float* tg   = (const float*)d_in[7];
    const float* tbe  = (const float*)d_in[8];
    const float* tw2  = (const float*)d_in[9];
    const float* tb2  = (const float*)d_in[10];
    const float* tw3  = (const float*)d_in[11];
    const float* tb3  = (const float*)d_in[12];
    const float* ow1  = (const float*)d_in[13];
    const float* ob1  = (const float*)d_in[14];
    const float* og   = (const float*)d_in[15];
    const float* obe  = (const float*)d_in[16];
    const float* ow2  = (const float*)d_in[17];
    const float* ob2  = (const float*)d_in[18];
    const float* ow3  = (const float*)d_in[19];
    const float* ob3  = (const float*)d_in[20];
    const float* z0m  = (const float*)d_in[21];
    const float* z0lv = (const float*)d_in[22];

    float* out0 = (float*)d_out;                   // obs_means   (B,T,32)
    float* out1 = out0 + (size_t)B_*T_*32;         // obs_logvars (B,T,32)
    float* out2 = out1 + (size_t)B_*T_*32;         // trans_means (B,T,5)
    float* out3 = out2 + (size_t)B_*T_*5;          // trans_logvars

    scan_kernel<<<B_, 512, 0, stream>>>(obs, Wih, Whh, bih, bhh,
                                        tw1, tb1, tg, tbe, tw2, tb2, tw3, tb3,
                                        z0m, z0lv, out2, out3);

    dec_kernel<<<DEC_BLOCKS, 512, 0, stream>>>(
        ow1, ob1, og, obe, ow2, ob2, ow3, ob3, out2, out0, out1);
}

// Round 4
// 3814.261 us; speedup vs baseline: 1.0345x; 1.0345x over previous
//
#include <hip/hip_runtime.h>

#define B_ 128
#define T_ 2048

typedef float vf32 __attribute__((ext_vector_type(32)));

__device__ __forceinline__ float fast_sigmoid(float x){
    return 1.0f / (1.0f + __expf(-x));
}
__device__ __forceinline__ float fast_tanh(float x){
    float a = fabsf(x);
    float e = __expf(2.0f*a);
    float r = 1.0f - 2.0f/(e + 1.0f);   // e=inf -> r=1, no NaN
    return (x < 0.0f) ? -r : r;
}

// ---------------------------------------------------------------------------
// Scan kernel: one workgroup per batch element b.
// threads   0..255 : LSTM  (thread g owns gate g; Wih row + Whh row in VGPRs)
// threads 256..511 : transition MLP, pipelined one step behind the LSTM
//
// CRITICAL register-layout invariant: BOTH paths keep their weights in the
// SAME three 32-wide vectors (wA0, wA1, wA2 = 96 VGPRs). Liveness is
// path-insensitive: in earlier revisions the trans path used separate
// vectors (wB, wC), making 144 vector values live at the loop head; the
// allocator capped at ~116 and rematerialized the rest as in-loop global
// loads -- every one of the 2048 serial steps stalled ~2000+ cy on vmcnt
// (VALUBusy 14%, dur flat at ~3.5 ms across 3 attempted fixes).
//   LSTM lane  (tid<256): wA0 = Wih row(32), wA1 = Whh[0..31], wA2 = Whh[32..63]
//   trans lane (tid>=256), row jr = q>>1, half ph = q&1:
//     wA0[0..31]  = t_w1[jr, ph*36 + 0..31]
//     wA1[0..3]   = t_w1[jr, ph*36 + 32..35]   (zeros past col 68)
//     wA1[4..31]  = t_w2 quarter-row [0..27]
//     wA2[0..3]   = t_w2 quarter-row [28..31]
//     wA2[4..19]  = t_w3 sixteenth (q<40)
// Total live vector elements: 96 (+ ~25 scalars/temps) -> fits the ~120-130
// the allocator will give, so nothing is remat'd inside the loop.
// ---------------------------------------------------------------------------
__global__ __launch_bounds__(512)
__attribute__((amdgpu_waves_per_eu(2, 2)))
void scan_kernel(
    const float* __restrict__ obs,
    const float* __restrict__ Wih,
    const float* __restrict__ Whh,
    const float* __restrict__ bih,
    const float* __restrict__ bhh,
    const float* __restrict__ tw1,
    const float* __restrict__ tb1,
    const float* __restrict__ tg,
    const float* __restrict__ tbeta,
    const float* __restrict__ tw2,
    const float* __restrict__ tb2,
    const float* __restrict__ tw3,
    const float* __restrict__ tb3,
    const float* __restrict__ z0m,
    const float* __restrict__ z0lv,
    float* __restrict__ out_tm,
    float* __restrict__ out_tlv)
{
    __shared__ __align__(16) float comb_s[2][72];   // [0..63]=h, [64..68]=z, [69..71]=0 pad
    __shared__ __align__(16) float obs_s[2][32];
    __shared__ float gates_s[256];
    __shared__ __align__(16) float h1_s[128];
    __shared__ float part_s[256];
    __shared__ float lnp[8];

    const int tid = threadIdx.x;
    const int b   = blockIdx.x;

    vf32 wA0, wA1, wA2;
    #pragma unroll
    for (int k = 0; k < 32; k++) { wA0[k] = 0.f; wA1[k] = 0.f; wA2[k] = 0.f; }

    float biasg = 0.f, b1r = 0.f, gr = 0.f, betar = 0.f, b2r = 0.f, b3r = 0.f;
    float c_st = 0.f;
    float a1v  = 0.f;
    float ld_carry = 0.f;

    if (tid < 256) {
        biasg = bih[tid] + bhh[tid];
        #pragma unroll
        for (int k = 0; k < 32; k++) wA0[k] = Wih[tid*32 + k];
        #pragma unroll
        for (int k = 0; k < 32; k++) wA1[k] = Whh[tid*64 + k];
        #pragma unroll
        for (int k = 0; k < 32; k++) wA2[k] = Whh[tid*64 + 32 + k];
    } else {
        const int q  = tid - 256;       // 0..255
        const int jr = q >> 1;          // t_w1 output row 0..127
        const int ph = q & 1;           // which half of the 69-dot
        // matvec1 weights: 36 per lane -> wA0[0..31], wA1[0..3]
        #pragma unroll
        for (int k = 0; k < 32; k++) {
            const int idx = ph*36 + k;
            const float v = tw1[jr*69 + (idx < 69 ? idx : 0)];
            wA0[k] = (idx < 69) ? v : 0.f;
        }
        #pragma unroll
        for (int k = 0; k < 4; k++) {
            const int idx = ph*36 + 32 + k;
            const float v = tw1[jr*69 + (idx < 69 ? idx : 0)];
            wA1[k] = (idx < 69) ? v : 0.f;
        }
        if (ph == 0) b1r = tb1[jr];     // bias added once per row (pair-combined)
        gr = tg[jr]; betar = tbeta[jr];
        // matvec2 weights: 32 per lane -> wA1[4..31], wA2[0..3]
        {
            const int j = q & 63, p = q >> 6;
            #pragma unroll
            for (int k = 0; k < 28; k++) wA1[4 + k] = tw2[j*128 + p*32 + k];
            #pragma unroll
            for (int k = 0; k < 4;  k++) wA2[k]     = tw2[j*128 + p*32 + 28 + k];
        }
        if (q < 64) b2r = tb2[q];
        // matvec3 weights: 16 per lane -> wA2[4..19]
        if (q < 40) {
            const int j = q >> 2, pp = q & 3;
            #pragma unroll
            for (int k = 0; k < 16; k++) wA2[4 + k] = tw3[j*64 + pp*16 + k];
            b3r = tb3[j];
        }
    }

    // LDS / output init
    if (tid < 64) comb_s[1][tid] = 0.f;           // h_{-1} = 0 (read at i=0)
    if (tid < 5) {
        comb_s[1][64 + tid] = z0m[tid];           // z for first trans step (t=1)
        out_tm [(size_t)b*T_*5 + tid] = z0m[tid];   // trans_means[t=0]  = z0_mean
        out_tlv[(size_t)b*T_*5 + tid] = z0lv[tid];  // trans_logvars[0]  = z0_log_var
    }
    if (tid < 3) { comb_s[0][69 + tid] = 0.f; comb_s[1][69 + tid] = 0.f; }
    if (tid >= 64 && tid < 69) comb_s[0][tid] = 0.f;   // z slot of buf 0 (defensive init)
    if (tid < 32) {
        obs_s[0][tid] = obs[(size_t)b*T_*32 + tid];       // t=0
        ld_carry      = obs[((size_t)b*T_ + 1)*32 + tid]; // t=1 in flight
    }
    __syncthreads();

    for (int i = 0; i <= T_; ++i) {
        const int cur = i & 1, prev = cur ^ 1;
        const bool lstm_on  = (i < T_);
        const bool trans_on = (i >= 2);   // processes t_tr = i-1 in [1, T-1]

        // ---- seg1: LSTM gate matvec  ||  trans matvec1 + LN partial reduce ----
        if (tid < 256) {
            if (lstm_on) {
                float acc0 = biasg, acc1 = 0.f, acc2 = 0.f, acc3 = 0.f;
                const float4* ob4 = (const float4*)obs_s[cur];
                #pragma unroll
                for (int k4 = 0; k4 < 8; k4++) {
                    float4 o = ob4[k4];
                    acc0 += wA0[k4*4+0]*o.x;
                    acc1 += wA0[k4*4+1]*o.y;
                    acc2 += wA0[k4*4+2]*o.z;
                    acc3 += wA0[k4*4+3]*o.w;
                }
                const float4* hb4 = (const float4*)comb_s[prev];
                #pragma unroll
                for (int k4 = 0; k4 < 8; k4++) {
                    float4 h = hb4[k4];
                    acc0 += wA1[k4*4+0]*h.x;
                    acc1 += wA1[k4*4+1]*h.y;
                    acc2 += wA1[k4*4+2]*h.z;
                    acc3 += wA1[k4*4+3]*h.w;
                }
                #pragma unroll
                for (int k4 = 0; k4 < 8; k4++) {
                    float4 h = hb4[8 + k4];
                    acc0 += wA2[k4*4+0]*h.x;
                    acc1 += wA2[k4*4+1]*h.y;
                    acc2 += wA2[k4*4+2]*h.z;
                    acc3 += wA2[k4*4+3]*h.w;
                }
                gates_s[tid] = (acc0 + acc1) + (acc2 + acc3);
            }
        } else {
            if (trans_on) {
                const int q  = tid - 256;
                const int ph = q & 1;
                float acc0 = b1r, acc1 = 0.f, acc2 = 0.f, acc3 = 0.f;
                const float4* cb4 = (const float4*)comb_s[prev] + ph*9;
                #pragma unroll
                for (int k4 = 0; k4 < 8; k4++) {
                    float4 cv = cb4[k4];
                    acc0 += wA0[k4*4+0]*cv.x;
                    acc1 += wA0[k4*4+1]*cv.y;
                    acc2 += wA0[k4*4+2]*cv.z;
                    acc3 += wA0[k4*4+3]*cv.w;
                }
                {
                    float4 cv = cb4[8];
                    acc0 += wA1[0]*cv.x;
                    acc1 += wA1[1]*cv.y;
                    acc2 += wA1[2]*cv.z;
                    acc3 += wA1[3]*cv.w;
                }
                float part = (acc0 + acc1) + (acc2 + acc3);
                part += __shfl_xor(part, 1, 64);   // combine the two half-dots
                a1v = part;
                // LN partial: each row appears twice per wave -> normalize /256
                float s1 = a1v, s2 = a1v*a1v;
                #pragma unroll
                for (int m = 1; m < 64; m <<= 1) {
                    s1 += __shfl_xor(s1, m, 64);
                    s2 += __shfl_xor(s2, m, 64);
                }
                const int wv = (tid >> 6) - 4;   // 0..3
                if ((tid & 63) == 0) { lnp[wv*2] = s1; lnp[wv*2 + 1] = s2; }
            }
        }
        __syncthreads();

        // ---- seg2: LSTM activations/state  ||  trans layernorm + tanh ----
        if (tid < 64) {
            if (lstm_on) {
                float iv = fast_sigmoid(gates_s[tid]);
                float fv = fast_sigmoid(gates_s[64 + tid]);
                float gv = fast_tanh   (gates_s[128 + tid]);
                float ov = fast_sigmoid(gates_s[192 + tid]);
                c_st = fv*c_st + iv*gv;
                comb_s[cur][tid] = ov * fast_tanh(c_st);
            }
        } else if (tid >= 256) {
            if (trans_on) {
                float mean = (lnp[0] + lnp[2] + lnp[4] + lnp[6]) * (1.0f/256.0f);
                float ms   = (lnp[1] + lnp[3] + lnp[5] + lnp[7]) * (1.0f/256.0f);
                float var  = fmaxf(ms - mean*mean, 0.0f);
                float rs   = rsqrtf(var + 1e-5f);
                if ((tid & 1) == 0)
                    h1_s[(tid - 256) >> 1] = fast_tanh((a1v - mean)*rs*gr + betar);
            }
        }
        __syncthreads();

        // ---- seg3: trans matvec2 partials  ||  LSTM waves prefetch obs ----
        if (tid >= 256) {
            if (trans_on) {
                const int q = tid - 256, p = q >> 6;
                float acc0 = 0.f, acc1 = 0.f, acc2 = 0.f, acc3 = 0.f;
                const float4* h14 = (const float4*)(h1_s + p*32);
                #pragma unroll
                for (int k4 = 0; k4 < 7; k4++) {
                    float4 hv = h14[k4];
                    acc0 += wA1[4+k4*4+0]*hv.x;
                    acc1 += wA1[4+k4*4+1]*hv.y;
                    acc2 += wA1[4+k4*4+2]*hv.z;
                    acc3 += wA1[4+k4*4+3]*hv.w;
                }
                {
                    float4 hv = h14[7];
                    acc0 += wA2[0]*hv.x;
                    acc1 += wA2[1]*hv.y;
                    acc2 += wA2[2]*hv.z;
                    acc3 += wA2[3]*hv.w;
                }
                part_s[q] = (acc0 + acc1) + (acc2 + acc3);
            }
        } else if (tid < 32) {
            const int t_w = i + 1, t_l = i + 2;
            if (t_w < T_) obs_s[t_w & 1][tid] = ld_carry;
            if (t_l < T_) ld_carry = obs[((size_t)b*T_ + t_l)*32 + tid];
        }
        __syncthreads();

        // ---- seg4 (wave 4 only, shuffle-based): h2, matvec3, outputs, z ----
        if (trans_on && tid >= 256 && tid < 320) {
            const int q = tid & 63;
            float h2v = fast_tanh(b2r + part_s[q] + part_s[64+q]
                                      + part_s[128+q] + part_s[192+q]);
            // lane q holds h2[q]; lane q computes partial dot of t_w3 row (q>>2)
            // over input chunk (q&3)*16 .. +15, gathered via shuffles.
            const int pp = q & 3;
            float acc = 0.f;
            #pragma unroll
            for (int k = 0; k < 16; k++)
                acc += wA2[4 + k] * __shfl(h2v, pp*16 + k, 64);
            acc += __shfl_xor(acc, 1, 64);
            acc += __shfl_xor(acc, 2, 64);   // lanes 4j..4j+3 now hold row-j total
            if (pp == 0 && q < 40) {
                const int j = q >> 2;        // 0..9
                float val = b3r + acc;
                const int t_tr = i - 1;
                const size_t row = (size_t)b*T_ + t_tr;
                if (j < 5) {
                    comb_s[cur][64 + j] = val;                      // z feedback
                    out_tm[row*5 + j] = val;
                } else {
                    out_tlv[row*5 + (j - 5)] = fminf(10.0f, fmaxf(-10.0f, val));
                }
            }
        }
        __syncthreads();
    }
}

// ---------------------------------------------------------------------------
// Observation decoder: one wave per row; weights in static LDS (~60 KB);
// h1/h2 are staged once per row into a per-wave LDS strip and re-read as
// BROADCAST float4 loads (same address across lanes = conflict-free, one DS
// op per 4 values). Accumulators split 4-way to break the serial FMA chain.
// ---------------------------------------------------------------------------
#define DEC_BLOCKS 512

__global__ __launch_bounds__(512) void dec_kernel(
    const float* __restrict__ ow1,
    const float* __restrict__ ob1,
    const float* __restrict__ og,
    const float* __restrict__ obeta,
    const float* __restrict__ ow2,
    const float* __restrict__ ob2,
    const float* __restrict__ ow3,
    const float* __restrict__ ob3,
    const float* __restrict__ tmeans,
    float* __restrict__ out_om,
    float* __restrict__ out_olv)
{
    __shared__ float w1s[640];    // [j*5+k]
    __shared__ float b1s[128], gs[128], bes[128];
    __shared__ float w2s[8192];   // [k*64+j] transposed
    __shared__ float b2s[64];
    __shared__ float w3s[4096];   // [k*64+j] transposed
    __shared__ float b3s[64];
    __shared__ __align__(16) float h1s[8][128];   // per-wave h1 strip
    __shared__ __align__(16) float h2s[8][64];    // per-wave h2 strip

    const int tid = threadIdx.x;
    for (int idx = tid; idx < 640; idx += 512) w1s[idx] = ow1[idx];
    for (int idx = tid; idx < 128; idx += 512) {
        b1s[idx] = ob1[idx]; gs[idx] = og[idx]; bes[idx] = obeta[idx];
    }
    for (int idx = tid; idx < 8192; idx += 512) {
        int k = idx >> 6, j = idx & 63;
        w2s[idx] = ow2[j*128 + k];
    }
    for (int idx = tid; idx < 4096; idx += 512) {
        int k = idx >> 6, j = idx & 63;
        w3s[idx] = ow3[j*64 + k];
    }
    for (int idx = tid; idx < 64; idx += 512) { b2s[idx] = ob2[idx]; b3s[idx] = ob3[idx]; }
    __syncthreads();

    const int lane   = tid & 63;
    const int wv     = tid >> 6;
    const int gwave  = (blockIdx.x * 512 + tid) >> 6;
    const int nwaves = DEC_BLOCKS * 8;
    const int j0 = lane, j1 = lane + 64;

    for (int row = gwave; row < B_*T_; row += nwaves) {
        const float z0v = tmeans[(size_t)row*5 + 0];
        const float z1v = tmeans[(size_t)row*5 + 1];
        const float z2v = tmeans[(size_t)row*5 + 2];
        const float z3v = tmeans[(size_t)row*5 + 3];
        const float z4v = tmeans[(size_t)row*5 + 4];

        // layer 1 (5 -> 128): lane holds outputs j0 and j1
        float a = b1s[j0] + w1s[j0*5+0]*z0v + w1s[j0*5+1]*z1v + w1s[j0*5+2]*z2v
                + w1s[j0*5+3]*z3v + w1s[j0*5+4]*z4v;
        float bb = b1s[j1] + w1s[j1*5+0]*z0v + w1s[j1*5+1]*z1v + w1s[j1*5+2]*z2v
                 + w1s[j1*5+3]*z3v + w1s[j1*5+4]*z4v;
        float s1 = a + bb, s2 = a*a + bb*bb;
        #pragma unroll
        for (int m = 1; m < 64; m <<= 1) {
            s1 += __shfl_xor(s1, m, 64);
            s2 += __shfl_xor(s2, m, 64);
        }
        const float mean = s1 * (1.0f/128.0f);
        const float var  = fmaxf(s2 * (1.0f/128.0f) - mean*mean, 0.0f);
        const float rs   = rsqrtf(var + 1e-5f);
        const float h1a  = fast_tanh((a  - mean)*rs*gs[j0] + bes[j0]);
        const float h1b  = fast_tanh((bb - mean)*rs*gs[j1] + bes[j1]);

        // stage h1 into the wave's private LDS strip (wave-synchronous)
        h1s[wv][lane]      = h1a;
        h1s[wv][64 + lane] = h1b;
        __builtin_amdgcn_wave_barrier();

        // layer 2 (128 -> 64): lane computes output j = lane.
        float acc2a = b2s[lane], acc2b = 0.f, acc2c = 0.f, acc2d = 0.f;
        const float4* h14 = (const float4*)(h1s[wv]);
        #pragma unroll
        for (int k4 = 0; k4 < 32; k4++) {
            float4 h = h14[k4];
            acc2a += h.x * w2s[(k4*4+0)*64 + lane];
            acc2b += h.y * w2s[(k4*4+1)*64 + lane];
            acc2c += h.z * w2s[(k4*4+2)*64 + lane];
            acc2d += h.w * w2s[(k4*4+3)*64 + lane];
        }
        const float h2v = fast_tanh(acc2a + acc2b + acc2c + acc2d);

        h2s[wv][lane] = h2v;
        __builtin_amdgcn_wave_barrier();

        // layer 3 (64 -> 64): lane computes output j = lane
        float acc3a = b3s[lane], acc3b = 0.f, acc3c = 0.f, acc3d = 0.f;
        const float4* h24 = (const float4*)(h2s[wv]);
        #pragma unroll
        for (int k4 = 0; k4 < 16; k4++) {
            float4 h = h24[k4];
            acc3a += h.x * w3s[(k4*4+0)*64 + lane];
            acc3b += h.y * w3s[(k4*4+1)*64 + lane];
            acc3c += h.z * w3s[(k4*4+2)*64 + lane];
            acc3d += h.w * w3s[(k4*4+3)*64 + lane];
        }
        const float acc3 = acc3a + acc3b + acc3c + acc3d;

        if (lane < 32) {
            out_om[(size_t)row*32 + lane] = acc3;
        } else {
            out_olv[(size_t)row*32 + (lane - 32)] = fminf(10.0f, fmaxf(-10.0f, acc3));
        }
    }
}

extern "C" void kernel_launch(void* const* d_in, const int* in_sizes, int n_in,
                              void* d_out, int out_size, void* d_ws, size_t ws_size,
                              hipStream_t stream) {
    const float* obs  = (const float*)d_in[0];
    const float* Wih  = (const float*)d_in[1];
    const float* Whh  = (const float*)d_in[2];
    const float* bih  = (const float*)d_in[3];
    const float* bhh  = (const float*)d_in[4];
    const float* tw1  = (const float*)d_in[5];
    const float* tb1  = (const float*)d_in[6];
    const float* tg   = (const float*)d_in[7];
    const float* tbe  = (const float*)d_in[8];
    const float* tw2  = (const float*)d_in[9];
    const float* tb2  = (const float*)d_in[10];
    const float* tw3  = (const float*)d_in[11];
    const float* tb3  = (const float*)d_in[12];
    const float* ow1  = (const float*)d_in[13];
    const float* ob1  = (const float*)d_in[14];
    const float* og   = (const float*)d_in[15];
    const float* obe  = (const float*)d_in[16];
    const float* ow2  = (const float*)d_in[17];
    const float* ob2  = (const float*)d_in[18];
    const float* ow3  = (const float*)d_in[19];
    const float* ob3  = (const float*)d_in[20];
    const float* z0m  = (const float*)d_in[21];
    const float* z0lv = (const float*)d_in[22];

    float* out0 = (float*)d_out;                   // obs_means   (B,T,32)
    float* out1 = out0 + (size_t)B_*T_*32;         // obs_logvars (B,T,32)
    float* out2 = out1 + (size_t)B_*T_*32;         // trans_means (B,T,5)
    float* out3 = out2 + (size_t)B_*T_*5;          // trans_logvars

    scan_kernel<<<B_, 512, 0, stream>>>(obs, Wih, Whh, bih, bhh,
                                        tw1, tb1, tg, tbe, tw2, tb2, tw3, tb3,
                                        z0m, z0lv, out2, out3);

    dec_kernel<<<DEC_BLOCKS, 512, 0, stream>>>(
        ow1, ob1, og, obe, ow2, ob2, ow3, ob3, out2, out0, out1);
}